// Round 1
// baseline (1064.165 us; speedup 1.0000x reference)
//
#include <hip/hip_runtime.h>
#include <math.h>

#define NN 16000
#define NE 256000
#define INV_SQRT_HD 0.35355339059327373f
#define LN_EPS 1e-5f

// ---------------- Kernel A: q = MLP(h)  [N,128] -> ws.q ----------------
__global__ __launch_bounds__(256) void qmlp_kernel(
    const float* __restrict__ h,
    const float* __restrict__ W1, const float* __restrict__ B1,
    const float* __restrict__ G,  const float* __restrict__ BE,
    const float* __restrict__ W2, const float* __restrict__ B2,
    float* __restrict__ qout)
{
    __shared__ float xT[128][20];
    __shared__ float hT[128][20];
    __shared__ float ps1[16][65];
    __shared__ float ps2[16][65];
    __shared__ float mu_s[16], rs_s[16];

    const int t = threadIdx.x;
    const int nb = blockIdx.x * 16;

    // load h tile transposed into LDS
    {
        const int ln = t & 15;          // node 0..15
        const int lc = (t >> 4) * 8;    // col base
        const float4* hp = (const float4*)(h + (size_t)(nb + ln) * 128 + lc);
        float4 a = hp[0], b = hp[1];
        xT[lc+0][ln] = a.x; xT[lc+1][ln] = a.y; xT[lc+2][ln] = a.z; xT[lc+3][ln] = a.w;
        xT[lc+4][ln] = b.x; xT[lc+5][ln] = b.y; xT[lc+6][ln] = b.z; xT[lc+7][ln] = b.w;
    }
    __syncthreads();

    const int n0 = (t & 3) * 4;     // 4 nodes
    const int jg = t >> 2;          // 0..63
    const int j0 = jg * 2;          // 2 cols

    float acc[4][2];
    {
        float c0 = B1[j0], c1 = B1[j0+1];
        #pragma unroll
        for (int n = 0; n < 4; ++n) { acc[n][0] = c0; acc[n][1] = c1; }
    }
    #pragma unroll 4
    for (int i = 0; i < 128; ++i) {
        float4 x = *(const float4*)&xT[i][n0];
        float2 w = *(const float2*)(W1 + i*128 + j0);
        acc[0][0] = fmaf(x.x, w.x, acc[0][0]);
        acc[1][0] = fmaf(x.y, w.x, acc[1][0]);
        acc[2][0] = fmaf(x.z, w.x, acc[2][0]);
        acc[3][0] = fmaf(x.w, w.x, acc[3][0]);
        acc[0][1] = fmaf(x.x, w.y, acc[0][1]);
        acc[1][1] = fmaf(x.y, w.y, acc[1][1]);
        acc[2][1] = fmaf(x.z, w.y, acc[2][1]);
        acc[3][1] = fmaf(x.w, w.y, acc[3][1]);
    }
    #pragma unroll
    for (int n = 0; n < 4; ++n) {
        ps1[n0+n][jg] = acc[n][0] + acc[n][1];
        ps2[n0+n][jg] = acc[n][0]*acc[n][0] + acc[n][1]*acc[n][1];
    }
    __syncthreads();
    if (t < 16) {
        float s1 = 0.f, s2 = 0.f;
        for (int k = 0; k < 64; ++k) { s1 += ps1[t][k]; s2 += ps2[t][k]; }
        float mu = s1 * (1.f/128.f);
        float var = s2 * (1.f/128.f) - mu*mu;
        mu_s[t] = mu;
        rs_s[t] = rsqrtf(var + LN_EPS);
    }
    __syncthreads();
    #pragma unroll
    for (int c = 0; c < 2; ++c) {
        float gj = G[j0+c], bj = BE[j0+c];
        #pragma unroll
        for (int n = 0; n < 4; ++n) {
            float v = (acc[n][c] - mu_s[n0+n]) * rs_s[n0+n] * gj + bj;
            hT[j0+c][n0+n] = fmaxf(v, 0.f);
        }
    }
    __syncthreads();
    float a2[4][2];
    {
        float c0 = B2[j0], c1 = B2[j0+1];
        #pragma unroll
        for (int n = 0; n < 4; ++n) { a2[n][0] = c0; a2[n][1] = c1; }
    }
    #pragma unroll 4
    for (int i = 0; i < 128; ++i) {
        float4 x = *(const float4*)&hT[i][n0];
        float2 w = *(const float2*)(W2 + i*128 + j0);
        a2[0][0] = fmaf(x.x, w.x, a2[0][0]);
        a2[1][0] = fmaf(x.y, w.x, a2[1][0]);
        a2[2][0] = fmaf(x.z, w.x, a2[2][0]);
        a2[3][0] = fmaf(x.w, w.x, a2[3][0]);
        a2[0][1] = fmaf(x.x, w.y, a2[0][1]);
        a2[1][1] = fmaf(x.y, w.y, a2[1][1]);
        a2[2][1] = fmaf(x.z, w.y, a2[2][1]);
        a2[3][1] = fmaf(x.w, w.y, a2[3][1]);
    }
    #pragma unroll
    for (int n = 0; n < 4; ++n) {
        qout[(size_t)(nb+n0+n)*128 + j0]     = a2[n][0];
        qout[(size_t)(nb+n0+n)*128 + j0 + 1] = a2[n][1];
    }
}

// ------------- Kernel B: per-edge k/v MLPs + scores + exp + denom -------------
__global__ __launch_bounds__(256) void edge_kernel(
    const float* __restrict__ h,
    const float* __restrict__ r_feat,
    const float* __restrict__ edge_feat,
    const int*   __restrict__ eidx,
    const float* __restrict__ kW1, const float* __restrict__ kB1,
    const float* __restrict__ kG,  const float* __restrict__ kBE,
    const float* __restrict__ kW2, const float* __restrict__ kB2,
    const float* __restrict__ vW1, const float* __restrict__ vB1,
    const float* __restrict__ vG,  const float* __restrict__ vBE,
    const float* __restrict__ vW2, const float* __restrict__ vB2,
    const float* __restrict__ ewW, const float* __restrict__ ewB,
    const float* __restrict__ q,
    float* __restrict__ ex_out, float* __restrict__ vw_out,
    float* __restrict__ denom)
{
    __shared__ float xT[280][33];      // X transposed: xT[i][e]
    __shared__ float hT[256][33];      // hidden transposed (k rows 0..127, v rows 128..255)
    __shared__ float ps1[32][33];
    __shared__ float ps2[32][33];
    __shared__ float mu_s[2][32], rs_s[2][32];
    __shared__ float ew_s[32];
    __shared__ int   dst_s[32];

    const int t = threadIdx.x;
    const int eb = blockIdx.x * 32;

    // ---- load X tile (transposed) ----
    {
        const int le = t >> 3;      // edge 0..31
        const int ls = t & 7;       // segment 0..7
        const int e = eb + le;
        const int dst = eidx[NE + e];
        if (ls == 0) dst_s[le] = dst;
        const int src = eidx[e];
        const float* hrow = (ls < 4) ? (h + (size_t)dst * 128) : (h + (size_t)src * 128);
        const int off = (ls & 3) * 32;
        const int ibase = 24 + ((ls < 4) ? 0 : 128) + off;
        const float4* hp = (const float4*)(hrow + off);
        #pragma unroll
        for (int v4 = 0; v4 < 8; ++v4) {
            float4 a = hp[v4];
            xT[ibase + v4*4 + 0][le] = a.x;
            xT[ibase + v4*4 + 1][le] = a.y;
            xT[ibase + v4*4 + 2][le] = a.z;
            xT[ibase + v4*4 + 3][le] = a.w;
        }
    }
    for (int p = t; p < 32*24; p += 256) {
        int le = p / 24, i = p % 24;
        int e = eb + le;
        float v = (i < 4) ? edge_feat[(size_t)e*4 + i] : r_feat[(size_t)e*20 + (i-4)];
        xT[i][le] = v;
    }
    if (t < 32) {
        int e = eb + t;
        float z = ewB[0];
        #pragma unroll
        for (int i = 0; i < 20; ++i) z = fmaf(r_feat[(size_t)e*20 + i], ewW[i], z);
        ew_s[t] = 1.f / (1.f + expf(-z));
    }
    __syncthreads();

    // ---- phase 1: hidden = X @ W1 (+b1), 256 cols (k:0..127, v:128..255) ----
    const int e0 = (t & 7) * 4;         // 4 edges
    const int jg = t >> 3;              // 0..31
    const int isv = (jg >= 16) ? 1 : 0;
    const int cj = (jg & 15) * 8;       // 8 cols within region
    const float* W1 = isv ? vW1 : kW1;
    const float* B1 = isv ? vB1 : kB1;

    float acc[4][8];
    #pragma unroll
    for (int jj = 0; jj < 8; ++jj) {
        float b = B1[cj + jj];
        acc[0][jj] = b; acc[1][jj] = b; acc[2][jj] = b; acc[3][jj] = b;
    }
    #pragma unroll 2
    for (int i = 0; i < 280; ++i) {
        float x0 = xT[i][e0+0], x1 = xT[i][e0+1], x2 = xT[i][e0+2], x3 = xT[i][e0+3];
        float w[8];
        *(float4*)&w[0] = *(const float4*)(W1 + i*128 + cj);
        *(float4*)&w[4] = *(const float4*)(W1 + i*128 + cj + 4);
        #pragma unroll
        for (int jj = 0; jj < 8; ++jj) {
            acc[0][jj] = fmaf(x0, w[jj], acc[0][jj]);
            acc[1][jj] = fmaf(x1, w[jj], acc[1][jj]);
            acc[2][jj] = fmaf(x2, w[jj], acc[2][jj]);
            acc[3][jj] = fmaf(x3, w[jj], acc[3][jj]);
        }
    }

    // ---- LN stats ----
    #pragma unroll
    for (int n = 0; n < 4; ++n) {
        float s1 = 0.f, s2 = 0.f;
        #pragma unroll
        for (int jj = 0; jj < 8; ++jj) { s1 += acc[n][jj]; s2 += acc[n][jj]*acc[n][jj]; }
        ps1[e0+n][jg] = s1;
        ps2[e0+n][jg] = s2;
    }
    __syncthreads();
    if (t < 64) {
        const int r = t >> 5, e = t & 31;
        float s1 = 0.f, s2 = 0.f;
        #pragma unroll
        for (int k = 0; k < 16; ++k) { s1 += ps1[e][r*16+k]; s2 += ps2[e][r*16+k]; }
        float mu = s1 * (1.f/128.f);
        float var = s2 * (1.f/128.f) - mu*mu;
        mu_s[r][e] = mu;
        rs_s[r][e] = rsqrtf(var + LN_EPS);
    }
    __syncthreads();

    // ---- normalize + ReLU -> hT ----
    {
        const float* G  = isv ? vG  : kG;
        const float* BE = isv ? vBE : kBE;
        #pragma unroll
        for (int jj = 0; jj < 8; ++jj) {
            float gj = G[cj+jj], bj = BE[cj+jj];
            #pragma unroll
            for (int n = 0; n < 4; ++n) {
                float hv = (acc[n][jj] - mu_s[isv][e0+n]) * rs_s[isv][e0+n] * gj + bj;
                hT[jg*8+jj][e0+n] = fmaxf(hv, 0.f);
            }
        }
    }
    __syncthreads();

    // ---- phase 2: k = hk @ W2k (128 cols), v = hv @ W2v (16 cols) ----
    const int j2 = jg * 4;   // 0..124
    float a2[4][4];
    #pragma unroll
    for (int jj = 0; jj < 4; ++jj) {
        float b = kB2[j2+jj];
        a2[0][jj]=b; a2[1][jj]=b; a2[2][jj]=b; a2[3][jj]=b;
    }
    #pragma unroll 2
    for (int i = 0; i < 128; ++i) {
        float x0 = hT[i][e0+0], x1 = hT[i][e0+1], x2 = hT[i][e0+2], x3 = hT[i][e0+3];
        float w[4];
        *(float4*)&w[0] = *(const float4*)(kW2 + i*128 + j2);
        #pragma unroll
        for (int jj = 0; jj < 4; ++jj) {
            a2[0][jj] = fmaf(x0, w[jj], a2[0][jj]);
            a2[1][jj] = fmaf(x1, w[jj], a2[1][jj]);
            a2[2][jj] = fmaf(x2, w[jj], a2[2][jj]);
            a2[3][jj] = fmaf(x3, w[jj], a2[3][jj]);
        }
    }
    // write k transposed into reused xT space: kT[j][e], stride 33
    {
        float* kT = &xT[0][0];
        #pragma unroll
        for (int jj = 0; jj < 4; ++jj)
            #pragma unroll
            for (int n = 0; n < 4; ++n)
                kT[(j2+jj)*33 + (e0+n)] = a2[n][jj];
    }
    // v-part: each thread one (edge, head-pair)
    {
        const int e = t & 31;
        const int hh0 = (t >> 5) * 2;
        float va0 = vB2[hh0], va1 = vB2[hh0+1];
        for (int i = 0; i < 128; ++i) {
            float x = hT[128+i][e];
            float2 w = *(const float2*)(vW2 + i*16 + hh0);
            va0 = fmaf(x, w.x, va0);
            va1 = fmaf(x, w.y, va1);
        }
        float sc = ew_s[e] * (1.f/16.f);   // fold e_w and head-mean
        vw_out[(size_t)(eb+e)*16 + hh0]     = va0 * sc;
        vw_out[(size_t)(eb+e)*16 + hh0 + 1] = va1 * sc;
    }
    __syncthreads();

    // ---- scores + exp + denom-atomics (no max-sub: softmax shift-invariant, scores O(0.1)) ----
    {
        const float* kT = &xT[0][0];
        #pragma unroll
        for (int rep = 0; rep < 2; ++rep) {
            int idx = rep*256 + t;
            int e = idx >> 4;
            int hh = idx & 15;
            int dst = dst_s[e];
            const float* qp = q + (size_t)dst*128 + hh*8;
            float s = 0.f;
            #pragma unroll
            for (int d = 0; d < 8; ++d)
                s = fmaf(kT[(hh*8+d)*33 + e], qp[d], s);
            float exv = expf(s * INV_SQRT_HD);
            ex_out[(size_t)(eb+e)*16 + hh] = exv;
            atomicAdd(&denom[(size_t)dst*16 + hh], exv);
        }
    }
}

// ------------- Kernel C: alpha = ex/denom, scatter out += sum_h(alpha*vw)*rel_x -------------
__global__ __launch_bounds__(256) void finalize_kernel(
    const int* __restrict__ eidx, const float* __restrict__ relx,
    const float* __restrict__ exb, const float* __restrict__ vwb,
    const float* __restrict__ den, float* __restrict__ out)
{
    const int e = blockIdx.x * 256 + threadIdx.x;
    const int dst = eidx[NE + e];
    const float4* ex4 = (const float4*)(exb + (size_t)e*16);
    const float4* vw4 = (const float4*)(vwb + (size_t)e*16);
    const float4* dn4 = (const float4*)(den + (size_t)dst*16);
    float s = 0.f;
    #pragma unroll
    for (int k = 0; k < 4; ++k) {
        float4 a = ex4[k], b = vw4[k], d = dn4[k];
        s += (a.x/d.x)*b.x + (a.y/d.y)*b.y + (a.z/d.z)*b.z + (a.w/d.w)*b.w;
    }
    float r0 = relx[(size_t)e*3+0], r1 = relx[(size_t)e*3+1], r2 = relx[(size_t)e*3+2];
    atomicAdd(&out[(size_t)dst*3+0], s*r0);
    atomicAdd(&out[(size_t)dst*3+1], s*r1);
    atomicAdd(&out[(size_t)dst*3+2], s*r2);
}

extern "C" void kernel_launch(void* const* d_in, const int* in_sizes, int n_in,
                              void* d_out, int out_size, void* d_ws, size_t ws_size,
                              hipStream_t stream) {
    const float* h         = (const float*)d_in[0];
    const float* rel_x     = (const float*)d_in[1];
    const float* r_feat    = (const float*)d_in[2];
    const float* edge_feat = (const float*)d_in[3];
    const int*   eidx      = (const int*)  d_in[4];
    const float* kW1 = (const float*)d_in[5];
    const float* kB1 = (const float*)d_in[6];
    const float* kG  = (const float*)d_in[7];
    const float* kBE = (const float*)d_in[8];
    const float* kW2 = (const float*)d_in[9];
    const float* kB2 = (const float*)d_in[10];
    const float* vW1 = (const float*)d_in[11];
    const float* vB1 = (const float*)d_in[12];
    const float* vG  = (const float*)d_in[13];
    const float* vBE = (const float*)d_in[14];
    const float* vW2 = (const float*)d_in[15];
    const float* vB2 = (const float*)d_in[16];
    const float* qW1 = (const float*)d_in[17];
    const float* qB1 = (const float*)d_in[18];
    const float* qG  = (const float*)d_in[19];
    const float* qBE = (const float*)d_in[20];
    const float* qW2 = (const float*)d_in[21];
    const float* qB2 = (const float*)d_in[22];
    const float* ewW = (const float*)d_in[23];
    const float* ewB = (const float*)d_in[24];

    float* ws  = (float*)d_ws;
    float* qbuf = ws;                          // N*128 = 2,048,000
    float* exb  = qbuf + (size_t)NN*128;       // E*16  = 4,096,000
    float* vwb  = exb + (size_t)NE*16;         // E*16  = 4,096,000
    float* den  = vwb + (size_t)NE*16;         // N*16  =   256,000
    float* outf = (float*)d_out;

    hipMemsetAsync(den, 0, (size_t)NN*16*sizeof(float), stream);
    hipMemsetAsync(outf, 0, (size_t)NN*3*sizeof(float), stream);

    qmlp_kernel<<<NN/16, 256, 0, stream>>>(h, qW1, qB1, qG, qBE, qW2, qB2, qbuf);
    edge_kernel<<<NE/32, 256, 0, stream>>>(h, r_feat, edge_feat, eidx,
                                           kW1, kB1, kG, kBE, kW2, kB2,
                                           vW1, vB1, vG, vBE, vW2, vB2,
                                           ewW, ewB, qbuf, exb, vwb, den);
    finalize_kernel<<<NE/256, 256, 0, stream>>>(eidx, rel_x, exb, vwb, den, outf);
}

// Round 2
// 334.914 us; speedup vs baseline: 3.1774x; 3.1774x over previous
//
#include <hip/hip_runtime.h>
#include <math.h>

#define NN 16000
#define NE 256000
#define INV_SQRT_HD 0.35355339059327373f
#define LN_EPS 1e-5f

typedef __attribute__((ext_vector_type(8))) short bf16x8;
typedef __attribute__((ext_vector_type(4))) float f32x4;

__device__ inline unsigned short f2bf(float x) {
    unsigned u = __float_as_uint(x);
    unsigned r = ((u >> 16) & 1u) + 0x7FFFu;
    return (unsigned short)((u + r) >> 16);
}

// ---------------- prep: pack weights to bf16 fragment order ----------------
// w1p[((s*16+mt)*64+l)*8+j] = W1cat[k=s*32+(l>>4)*8+j][col=mt*16+(l&15)], k<280 else 0
// w2p[((s2*9+ct)*64+l)*8+j] = W2cat[k=s2*32+(l>>4)*8+j][col=ct*16+(l&15)] (ct=8 -> vW2)
__global__ __launch_bounds__(256) void prep_kernel(
    const float* __restrict__ kW1, const float* __restrict__ vW1,
    const float* __restrict__ kW2, const float* __restrict__ vW2,
    unsigned short* __restrict__ w1p, unsigned short* __restrict__ w2p)
{
    int idx = blockIdx.x * 256 + threadIdx.x;
    if (idx < 73728) {
        int j = idx & 7, l = (idx >> 3) & 63, mtc = (idx >> 9) & 15, s = idx >> 13;
        int k = s * 32 + (l >> 4) * 8 + j;
        int col = mtc * 16 + (l & 15);
        float v = 0.f;
        if (k < 280) v = (col < 128) ? kW1[(size_t)k * 128 + col] : vW1[(size_t)k * 128 + col - 128];
        w1p[idx] = f2bf(v);
    } else if (idx < 73728 + 18432) {
        int i2 = idx - 73728;
        int j = i2 & 7, l = (i2 >> 3) & 63;
        int sc = i2 >> 9;              // 0..35
        int ct = sc % 9, s2 = sc / 9;
        int k = s2 * 32 + (l >> 4) * 8 + j;
        float v = (ct < 8) ? kW2[(size_t)k * 128 + ct * 16 + (l & 15)]
                           : vW2[(size_t)k * 16 + (l & 15)];
        w2p[i2] = f2bf(v);
    }
}

// ---------------- Kernel A: q = MLP(h) (fp32, small) ----------------
__global__ __launch_bounds__(256) void qmlp_kernel(
    const float* __restrict__ h,
    const float* __restrict__ W1, const float* __restrict__ B1,
    const float* __restrict__ G,  const float* __restrict__ BE,
    const float* __restrict__ W2, const float* __restrict__ B2,
    float* __restrict__ qout)
{
    __shared__ float xT[128][20];
    __shared__ float hT[128][20];
    __shared__ float ps1[16][65];
    __shared__ float ps2[16][65];
    __shared__ float mu_s[16], rs_s[16];

    const int t = threadIdx.x;
    const int nb = blockIdx.x * 16;

    {
        const int ln = t & 15;
        const int lc = (t >> 4) * 8;
        const float4* hp = (const float4*)(h + (size_t)(nb + ln) * 128 + lc);
        float4 a = hp[0], b = hp[1];
        xT[lc+0][ln] = a.x; xT[lc+1][ln] = a.y; xT[lc+2][ln] = a.z; xT[lc+3][ln] = a.w;
        xT[lc+4][ln] = b.x; xT[lc+5][ln] = b.y; xT[lc+6][ln] = b.z; xT[lc+7][ln] = b.w;
    }
    __syncthreads();

    const int n0 = (t & 3) * 4;
    const int jg = t >> 2;
    const int j0 = jg * 2;

    float acc[4][2];
    {
        float c0 = B1[j0], c1 = B1[j0+1];
        #pragma unroll
        for (int n = 0; n < 4; ++n) { acc[n][0] = c0; acc[n][1] = c1; }
    }
    #pragma unroll 4
    for (int i = 0; i < 128; ++i) {
        float4 x = *(const float4*)&xT[i][n0];
        float2 w = *(const float2*)(W1 + i*128 + j0);
        acc[0][0] = fmaf(x.x, w.x, acc[0][0]);
        acc[1][0] = fmaf(x.y, w.x, acc[1][0]);
        acc[2][0] = fmaf(x.z, w.x, acc[2][0]);
        acc[3][0] = fmaf(x.w, w.x, acc[3][0]);
        acc[0][1] = fmaf(x.x, w.y, acc[0][1]);
        acc[1][1] = fmaf(x.y, w.y, acc[1][1]);
        acc[2][1] = fmaf(x.z, w.y, acc[2][1]);
        acc[3][1] = fmaf(x.w, w.y, acc[3][1]);
    }
    #pragma unroll
    for (int n = 0; n < 4; ++n) {
        ps1[n0+n][jg] = acc[n][0] + acc[n][1];
        ps2[n0+n][jg] = acc[n][0]*acc[n][0] + acc[n][1]*acc[n][1];
    }
    __syncthreads();
    if (t < 16) {
        float s1 = 0.f, s2 = 0.f;
        for (int k = 0; k < 64; ++k) { s1 += ps1[t][k]; s2 += ps2[t][k]; }
        float mu = s1 * (1.f/128.f);
        float var = s2 * (1.f/128.f) - mu*mu;
        mu_s[t] = mu;
        rs_s[t] = rsqrtf(var + LN_EPS);
    }
    __syncthreads();
    #pragma unroll
    for (int c = 0; c < 2; ++c) {
        float gj = G[j0+c], bj = BE[j0+c];
        #pragma unroll
        for (int n = 0; n < 4; ++n) {
            float v = (acc[n][c] - mu_s[n0+n]) * rs_s[n0+n] * gj + bj;
            hT[j0+c][n0+n] = fmaxf(v, 0.f);
        }
    }
    __syncthreads();
    float a2[4][2];
    {
        float c0 = B2[j0], c1 = B2[j0+1];
        #pragma unroll
        for (int n = 0; n < 4; ++n) { a2[n][0] = c0; a2[n][1] = c1; }
    }
    #pragma unroll 4
    for (int i = 0; i < 128; ++i) {
        float4 x = *(const float4*)&hT[i][n0];
        float2 w = *(const float2*)(W2 + i*128 + j0);
        a2[0][0] = fmaf(x.x, w.x, a2[0][0]);
        a2[1][0] = fmaf(x.y, w.x, a2[1][0]);
        a2[2][0] = fmaf(x.z, w.x, a2[2][0]);
        a2[3][0] = fmaf(x.w, w.x, a2[3][0]);
        a2[0][1] = fmaf(x.x, w.y, a2[0][1]);
        a2[1][1] = fmaf(x.y, w.y, a2[1][1]);
        a2[2][1] = fmaf(x.z, w.y, a2[2][1]);
        a2[3][1] = fmaf(x.w, w.y, a2[3][1]);
    }
    #pragma unroll
    for (int n = 0; n < 4; ++n) {
        qout[(size_t)(nb+n0+n)*128 + j0]     = a2[n][0];
        qout[(size_t)(nb+n0+n)*128 + j0 + 1] = a2[n][1];
    }
}

// ------------- Kernel B: MFMA edge k/v MLPs + scores + exp + denom -------------
// 64 edges/block, 4 waves. Both GEMMs transposed: D[row=weightcol][col=edge].
__global__ __launch_bounds__(256, 2) void edge_kernel(
    const float* __restrict__ h,
    const float* __restrict__ r_feat,
    const float* __restrict__ edge_feat,
    const int*   __restrict__ eidx,
    const float* __restrict__ kB1, const float* __restrict__ kG, const float* __restrict__ kBE,
    const float* __restrict__ vB1, const float* __restrict__ vG, const float* __restrict__ vBE,
    const float* __restrict__ kB2, const float* __restrict__ vB2,
    const float* __restrict__ ewW, const float* __restrict__ ewB,
    const unsigned short* __restrict__ w1p, const unsigned short* __restrict__ w2p,
    const float* __restrict__ q,
    float* __restrict__ ex_out, float* __restrict__ vw_out, float* __restrict__ denom)
{
    __shared__ __align__(16) unsigned char xs_raw[40960];  // X bf16 [64][stride 640B]; later qs f32 [64][132]
    __shared__ __align__(16) unsigned char hs_raw[32768];  // hidden bf16 2 regions x [64][256B]
    __shared__ float2 lnb[4][64];
    __shared__ float2 murs[2][64];
    __shared__ float2 gbe[256];
    __shared__ float  gb1[256];
    __shared__ float  gb2[144];
    __shared__ int    dst_s[64];
    __shared__ float  ew_s[64];

    const int t = threadIdx.x;
    const int eb = blockIdx.x * 64;
    const int w = t >> 6, l = t & 63, lrow = l & 15, lgrp = l >> 4;

    // ---- stage X (bf16, swizzled row-major, stride 640B = 40 slots) ----
    {
        const int le = t & 63, p = t >> 6;
        const int e = eb + le;
        const int row = (p < 2) ? eidx[NE + e] : eidx[e];
        const float* hp = h + (size_t)row * 128 + (p & 1) * 64;
        const unsigned swz = (unsigned)((le & 7) << 4);
        unsigned char* xrow = xs_raw + le * 640;
        #pragma unroll
        for (int i = 0; i < 16; ++i) {
            float4 f = *(const float4*)(hp + i * 4);
            ushort4 u;
            u.x = f2bf(f.x); u.y = f2bf(f.y); u.z = f2bf(f.z); u.w = f2bf(f.w);
            unsigned kb = (unsigned)(48 + p * 128 + i * 8);
            *(ushort4*)(xrow + (kb ^ swz)) = u;
        }
    }
    if (t < 192) {
        const int le = t / 3, fi = t - (t / 3) * 3;
        const int e = eb + le;
        const unsigned swz = (unsigned)((le & 7) << 4);
        unsigned char* xrow = xs_raw + le * 640;
        float fa[8];
        if (fi == 0) {
            *(float4*)&fa[0] = *(const float4*)(edge_feat + (size_t)e * 4);
            *(float4*)&fa[4] = *(const float4*)(r_feat + (size_t)e * 20);
        } else {
            *(float4*)&fa[0] = *(const float4*)(r_feat + (size_t)e * 20 + fi * 8 - 4);
            *(float4*)&fa[4] = *(const float4*)(r_feat + (size_t)e * 20 + fi * 8);
        }
        ushort4 u0, u1;
        u0.x = f2bf(fa[0]); u0.y = f2bf(fa[1]); u0.z = f2bf(fa[2]); u0.w = f2bf(fa[3]);
        u1.x = f2bf(fa[4]); u1.y = f2bf(fa[5]); u1.z = f2bf(fa[6]); u1.w = f2bf(fa[7]);
        unsigned kb0 = (unsigned)(fi * 16);
        *(ushort4*)(xrow + (kb0 ^ swz)) = u0;
        *(ushort4*)(xrow + ((kb0 + 8) ^ swz)) = u1;
    }
    if (t >= 192) {
        const int le = t - 192;
        const unsigned swz = (unsigned)((le & 7) << 4);
        unsigned char* xrow = xs_raw + le * 640;
        ushort4 z; z.x = 0; z.y = 0; z.z = 0; z.w = 0;
        #pragma unroll
        for (int i = 0; i < 10; ++i)
            *(ushort4*)(xrow + ((unsigned)(560 + i * 8) ^ swz)) = z;
    }
    if (t < 64) {
        const int e = eb + t;
        dst_s[t] = eidx[NE + e];
        float z = ewB[0];
        #pragma unroll
        for (int i = 0; i < 20; ++i) z = fmaf(r_feat[(size_t)e * 20 + i], ewW[i], z);
        ew_s[t] = (1.f / (1.f + expf(-z))) * (1.f / 16.f);  // fold e_w and head-mean
    }
    gbe[t] = make_float2((t < 128) ? kG[t] : vG[t - 128],
                         (t < 128) ? kBE[t] : vBE[t - 128]);
    gb1[t] = (t < 128) ? kB1[t] : vB1[t - 128];
    if (t < 144) gb2[t] = (t < 128) ? kB2[t] : vB2[t - 128];
    __syncthreads();

    // ---- GEMM1: hiddenT[256 cols][64 e] = W1T x XT, K=288 ----
    f32x4 acc1[4][4];
    #pragma unroll
    for (int mt = 0; mt < 4; ++mt) {
        const int k0 = (w * 4 + mt) * 16 + lgrp * 4;
        const float b0 = gb1[k0], b1 = gb1[k0 + 1], b2 = gb1[k0 + 2], b3 = gb1[k0 + 3];
        #pragma unroll
        for (int nt = 0; nt < 4; ++nt) {
            acc1[mt][nt][0] = b0; acc1[mt][nt][1] = b1;
            acc1[mt][nt][2] = b2; acc1[mt][nt][3] = b3;
        }
    }
    #pragma unroll 1
    for (int s = 0; s < 9; ++s) {
        bf16x8 af[4], xf[4];
        #pragma unroll
        for (int mt = 0; mt < 4; ++mt)
            af[mt] = *(const bf16x8*)(w1p + (size_t)((s * 16 + w * 4 + mt) * 64 + l) * 8);
        #pragma unroll
        for (int nt = 0; nt < 4; ++nt) {
            const int e_loc = nt * 16 + lrow;
            xf[nt] = *(const bf16x8*)(xs_raw + e_loc * 640 +
                     ((unsigned)(s * 64 + lgrp * 16) ^ (unsigned)((e_loc & 7) << 4)));
        }
        #pragma unroll
        for (int mt = 0; mt < 4; ++mt)
            #pragma unroll
            for (int nt = 0; nt < 4; ++nt)
                acc1[mt][nt] = __builtin_amdgcn_mfma_f32_16x16x32_bf16(af[mt], xf[nt], acc1[mt][nt], 0, 0, 0);
    }

    // ---- LN stats (per edge over its 128-col region) ----
    #pragma unroll
    for (int nt = 0; nt < 4; ++nt) {
        float p1 = 0.f, p2 = 0.f;
        #pragma unroll
        for (int mt = 0; mt < 4; ++mt)
            #pragma unroll
            for (int r = 0; r < 4; ++r) { float v = acc1[mt][nt][r]; p1 += v; p2 += v * v; }
        p1 += __shfl_xor(p1, 16); p2 += __shfl_xor(p2, 16);
        p1 += __shfl_xor(p1, 32); p2 += __shfl_xor(p2, 32);
        if (l < 16) lnb[w][nt * 16 + l] = make_float2(p1, p2);
    }
    __syncthreads();

    // q gather (issue early; X region is dead now)
    float4 qreg[8];
    {
        const int le = t >> 2, part = t & 3;
        const float* qp = q + (size_t)dst_s[le] * 128 + part * 32;
        #pragma unroll
        for (int i = 0; i < 8; ++i) qreg[i] = *(const float4*)(qp + i * 4);
    }
    if (t < 128) {
        const int region = t >> 6, e = t & 63;
        float2 a = lnb[region * 2][e], b = lnb[region * 2 + 1][e];
        float s1 = a.x + b.x, s2 = a.y + b.y;
        float mu = s1 * (1.f / 128.f);
        float var = s2 * (1.f / 128.f) - mu * mu;
        murs[region][e] = make_float2(mu, rsqrtf(var + LN_EPS));
    }
    __syncthreads();

    // ---- normalize + ReLU + bf16 -> hidden LDS (row-major [e][128], swizzled) ----
    {
        const int region = w >> 1;
        unsigned char* hbase = hs_raw + region * 16384;
        #pragma unroll
        for (int mt = 0; mt < 4; ++mt) {
            const int k0 = (w * 4 + mt) * 16 + lgrp * 4;
            const int kc = k0 & 127;
            const float2 g0 = gbe[k0], g1 = gbe[k0 + 1], g2 = gbe[k0 + 2], g3 = gbe[k0 + 3];
            #pragma unroll
            for (int nt = 0; nt < 4; ++nt) {
                const int e_loc = nt * 16 + lrow;
                const float2 mr = murs[region][e_loc];
                ushort4 u;
                u.x = f2bf(fmaxf((acc1[mt][nt][0] - mr.x) * mr.y * g0.x + g0.y, 0.f));
                u.y = f2bf(fmaxf((acc1[mt][nt][1] - mr.x) * mr.y * g1.x + g1.y, 0.f));
                u.z = f2bf(fmaxf((acc1[mt][nt][2] - mr.x) * mr.y * g2.x + g2.y, 0.f));
                u.w = f2bf(fmaxf((acc1[mt][nt][3] - mr.x) * mr.y * g3.x + g3.y, 0.f));
                *(ushort4*)(hbase + e_loc * 256 +
                    ((unsigned)(kc * 2) ^ (unsigned)((e_loc & 7) << 4))) = u;
            }
        }
    }
    // park q into qs (overwrites X region)
    float* qs = (float*)xs_raw;  // [64][132]
    {
        const int le = t >> 2, part = t & 3;
        #pragma unroll
        for (int i = 0; i < 8; ++i)
            *(float4*)(qs + (size_t)le * 132 + part * 32 + i * 4) = qreg[i];
    }
    __syncthreads();

    // ---- GEMM2: kT[128][64] + vT[16][64] = W2T x hiddenT, K=128 ----
    f32x4 acc2[2][4], accv;
    #pragma unroll
    for (int km = 0; km < 2; ++km) {
        const int c0 = (w * 2 + km) * 16 + lgrp * 4;
        #pragma unroll
        for (int nt = 0; nt < 4; ++nt) {
            acc2[km][nt][0] = gb2[c0];     acc2[km][nt][1] = gb2[c0 + 1];
            acc2[km][nt][2] = gb2[c0 + 2]; acc2[km][nt][3] = gb2[c0 + 3];
        }
    }
    {
        const int cv = 128 + lgrp * 4;
        accv[0] = gb2[cv]; accv[1] = gb2[cv + 1]; accv[2] = gb2[cv + 2]; accv[3] = gb2[cv + 3];
    }
    #pragma unroll 1
    for (int s2 = 0; s2 < 4; ++s2) {
        bf16x8 a0 = *(const bf16x8*)(w2p + (size_t)((s2 * 9 + w * 2) * 64 + l) * 8);
        bf16x8 a1 = *(const bf16x8*)(w2p + (size_t)((s2 * 9 + w * 2 + 1) * 64 + l) * 8);
        bf16x8 av = *(const bf16x8*)(w2p + (size_t)((s2 * 9 + 8) * 64 + l) * 8);
        const unsigned kb = (unsigned)(s2 * 64 + lgrp * 16);
        bf16x8 hb[4];
        #pragma unroll
        for (int nt = 0; nt < 4; ++nt) {
            const int e_loc = nt * 16 + lrow;
            hb[nt] = *(const bf16x8*)(hs_raw + e_loc * 256 + (kb ^ (unsigned)((e_loc & 7) << 4)));
        }
        {
            const int e_loc = w * 16 + lrow;
            bf16x8 hv = *(const bf16x8*)(hs_raw + 16384 + e_loc * 256 + (kb ^ (unsigned)((e_loc & 7) << 4)));
            accv = __builtin_amdgcn_mfma_f32_16x16x32_bf16(av, hv, accv, 0, 0, 0);
        }
        #pragma unroll
        for (int nt = 0; nt < 4; ++nt) {
            acc2[0][nt] = __builtin_amdgcn_mfma_f32_16x16x32_bf16(a0, hb[nt], acc2[0][nt], 0, 0, 0);
            acc2[1][nt] = __builtin_amdgcn_mfma_f32_16x16x32_bf16(a1, hb[nt], acc2[1][nt], 0, 0, 0);
        }
    }

    // ---- v output: lane holds v[e=w*16+lrow][head=lgrp*4+r] ----
    {
        const int e_loc = w * 16 + lrow;
        const float sc = ew_s[e_loc];
        float4 vo;
        vo.x = accv[0] * sc; vo.y = accv[1] * sc; vo.z = accv[2] * sc; vo.w = accv[3] * sc;
        *(float4*)(vw_out + (size_t)(eb + e_loc) * 16 + lgrp * 4) = vo;
    }

    // ---- scores + exp + denom atomics ----
    #pragma unroll
    for (int km = 0; km < 2; ++km) {
        const int mt2 = w * 2 + km;
        #pragma unroll
        for (int nt = 0; nt < 4; ++nt) {
            const int e_loc = nt * 16 + lrow;
            const float* qrow = qs + (size_t)e_loc * 132 + mt2 * 16 + lgrp * 4;
            float sp = acc2[km][nt][0] * qrow[0] + acc2[km][nt][1] * qrow[1]
                     + acc2[km][nt][2] * qrow[2] + acc2[km][nt][3] * qrow[3];
            sp += __shfl_xor(sp, 16);
            if ((l & 16) == 0) {
                const float exv = expf(sp * INV_SQRT_HD);
                const int hh = mt2 * 2 + (lgrp >> 1);
                const int dst = dst_s[e_loc];
                ex_out[(size_t)(eb + e_loc) * 16 + hh] = exv;
                atomicAdd(&denom[(size_t)dst * 16 + hh], exv);
            }
        }
    }
}

// ------------- Kernel C: alpha = ex/denom, scatter out += sum_h(alpha*vw)*rel_x -------------
__global__ __launch_bounds__(256) void finalize_kernel(
    const int* __restrict__ eidx, const float* __restrict__ relx,
    const float* __restrict__ exb, const float* __restrict__ vwb,
    const float* __restrict__ den, float* __restrict__ out)
{
    const int e = blockIdx.x * 256 + threadIdx.x;
    const int dst = eidx[NE + e];
    const float4* ex4 = (const float4*)(exb + (size_t)e*16);
    const float4* vw4 = (const float4*)(vwb + (size_t)e*16);
    const float4* dn4 = (const float4*)(den + (size_t)dst*16);
    float s = 0.f;
    #pragma unroll
    for (int k = 0; k < 4; ++k) {
        float4 a = ex4[k], b = vw4[k], d = dn4[k];
        s += (a.x/d.x)*b.x + (a.y/d.y)*b.y + (a.z/d.z)*b.z + (a.w/d.w)*b.w;
    }
    float r0 = relx[(size_t)e*3+0], r1 = relx[(size_t)e*3+1], r2 = relx[(size_t)e*3+2];
    atomicAdd(&out[(size_t)dst*3+0], s*r0);
    atomicAdd(&out[(size_t)dst*3+1], s*r1);
    atomicAdd(&out[(size_t)dst*3+2], s*r2);
}

extern "C" void kernel_launch(void* const* d_in, const int* in_sizes, int n_in,
                              void* d_out, int out_size, void* d_ws, size_t ws_size,
                              hipStream_t stream) {
    const float* h         = (const float*)d_in[0];
    const float* rel_x     = (const float*)d_in[1];
    const float* r_feat    = (const float*)d_in[2];
    const float* edge_feat = (const float*)d_in[3];
    const int*   eidx      = (const int*)  d_in[4];
    const float* kW1 = (const float*)d_in[5];
    const float* kB1 = (const float*)d_in[6];
    const float* kG  = (const float*)d_in[7];
    const float* kBE = (const float*)d_in[8];
    const float* kW2 = (const float*)d_in[9];
    const float* kB2 = (const float*)d_in[10];
    const float* vW1 = (const float*)d_in[11];
    const float* vB1 = (const float*)d_in[12];
    const float* vG  = (const float*)d_in[13];
    const float* vBE = (const float*)d_in[14];
    const float* vW2 = (const float*)d_in[15];
    const float* vB2 = (const float*)d_in[16];
    const float* qW1 = (const float*)d_in[17];
    const float* qB1 = (const float*)d_in[18];
    const float* qG  = (const float*)d_in[19];
    const float* qBE = (const float*)d_in[20];
    const float* qW2 = (const float*)d_in[21];
    const float* qB2 = (const float*)d_in[22];
    const float* ewW = (const float*)d_in[23];
    const float* ewB = (const float*)d_in[24];

    float* ws   = (float*)d_ws;
    float* qbuf = ws;                          // N*128
    float* exb  = qbuf + (size_t)NN*128;       // E*16
    float* vwb  = exb + (size_t)NE*16;         // E*16
    float* den  = vwb + (size_t)NE*16;         // N*16
    unsigned short* w1p = (unsigned short*)(den + (size_t)NN*16);   // 73728 bf16
    unsigned short* w2p = w1p + 73728;                              // 18432 bf16
    float* outf = (float*)d_out;

    hipMemsetAsync(den, 0, (size_t)NN*16*sizeof(float), stream);
    hipMemsetAsync(outf, 0, (size_t)NN*3*sizeof(float), stream);

    prep_kernel<<<(73728 + 18432 + 255) / 256, 256, 0, stream>>>(kW1, vW1, kW2, vW2, w1p, w2p);
    qmlp_kernel<<<NN/16, 256, 0, stream>>>(h, qW1, qB1, qG, qBE, qW2, qB2, qbuf);
    edge_kernel<<<NE/64, 256, 0, stream>>>(h, r_feat, edge_feat, eidx,
                                           kB1, kG, kBE, vB1, vG, vBE,
                                           kB2, vB2, ewW, ewB, w1p, w2p, qbuf,
                                           exb, vwb, den);
    finalize_kernel<<<NE/256, 256, 0, stream>>>(eidx, rel_x, exb, vwb, den, outf);
}